// Round 10
// baseline (63.545 us; speedup 1.0000x reference)
//
#include <hip/hip_runtime.h>
#include <hip/hip_bf16.h>

#define NB 16   // batch
#define NN 512  // input capsules (n)
#define DI 256  // input dim (i)
#define NC 64   // output capsules (c)
#define ND 128  // capsule dim (d)
#define FO 8192 // NC*ND
#define NP 8    // n-tiles (split-k partials for y), 64 n each

typedef __attribute__((ext_vector_type(8))) short short8v;
typedef __attribute__((ext_vector_type(4))) short short4v;
typedef __attribute__((ext_vector_type(4))) float f32x4;
typedef unsigned short us16;

__device__ __forceinline__ us16 f2b(float f) {
  union { __hip_bfloat16 h; us16 u; } cv; cv.h = __float2bfloat16(f); return cv.u;
}
__device__ __forceinline__ float b2f(us16 u) {
  union { unsigned u; float f; } cv; cv.u = ((unsigned)u) << 16; return cv.f;
}

// ---------------------------------------------------------------------------
// k_pre: task-split prep.
//  [0,512):     khT[c][d][i] AND kh[i][cd] bf16 from one staged kern tile
//  [512,1024):  xh[b][n][i], xhT[b][i][n]  bf16 casts of x
//  [1024,1088): xsum_p[q][b][i] colsum quarters
__global__ __launch_bounds__(256) void k_pre(const float* __restrict__ x,
                                             const float* __restrict__ kern,
                                             us16* __restrict__ khT,
                                             us16* __restrict__ kh,
                                             us16* __restrict__ xh,
                                             us16* __restrict__ xhT,
                                             float* __restrict__ xsum_p) {
  int task = blockIdx.x;
  int tid = threadIdx.x;

  if (task < 512) {  // khT + kh
    int c = task >> 3, i0 = (task & 7) * 32;
    __shared__ float buf[32][129];
#pragma unroll
    for (int k = 0; k < 4; ++k) {
      int e4 = tid + k * 256;
      int r = e4 >> 5, dq = e4 & 31;
      float4 v = *(const float4*)(kern + (size_t)(i0 + r) * FO + c * ND + dq * 4);
      buf[r][dq * 4 + 0] = v.x; buf[r][dq * 4 + 1] = v.y;
      buf[r][dq * 4 + 2] = v.z; buf[r][dq * 4 + 3] = v.w;
    }
    __syncthreads();
#pragma unroll
    for (int k = 0; k < 16; ++k) {  // khT transpose out
      int e = tid + k * 256;
      int il = e & 31, d = e >> 5;
      khT[((size_t)c * ND + d) * DI + i0 + il] = f2b(buf[il][d]);
    }
    {  // kh same-layout cast out
      int r = tid >> 3, dg = (tid & 7) * 16;
      us16 tmp[16];
#pragma unroll
      for (int e = 0; e < 16; ++e) tmp[e] = f2b(buf[r][dg + e]);
      us16* dst = kh + (size_t)(i0 + r) * FO + c * ND + dg;
      *(short8v*)dst = *(short8v*)tmp;
      *(short8v*)(dst + 8) = *(short8v*)(tmp + 8);
    }
  } else if (task < 1024) {  // xh / xhT
    int idx = task - 512;
    int b = idx >> 5, rem = idx & 31;
    int nb = (rem >> 2) * 64, ib = (rem & 3) * 64;
    __shared__ float buf2[64][68];
#pragma unroll
    for (int k = 0; k < 4; ++k) {
      int e4 = tid + k * 256;
      int nl = e4 >> 4, q4 = e4 & 15;
      float4 v = *(const float4*)(x + ((size_t)b * NN + nb + nl) * DI + ib + q4 * 4);
      *(float4*)&buf2[nl][q4 * 4] = v;
    }
    __syncthreads();
    {
      int nl = tid >> 2, ig = (tid & 3) * 16;
      us16 tmp[16];
#pragma unroll
      for (int e = 0; e < 16; ++e) tmp[e] = f2b(buf2[nl][ig + e]);
      us16* dst = xh + ((size_t)b * NN + nb + nl) * DI + ib + ig;
      *(short8v*)dst = *(short8v*)tmp;
      *(short8v*)(dst + 8) = *(short8v*)(tmp + 8);
    }
    {
      int il = tid & 63, ng = tid >> 6;
      us16 tmp[16];
#pragma unroll
      for (int e = 0; e < 16; ++e) tmp[e] = f2b(buf2[ng * 16 + e][il]);
      us16* dst = xhT + ((size_t)b * DI + ib + il) * NN + nb + ng * 16;
      *(short8v*)dst = *(short8v*)tmp;
      *(short8v*)(dst + 8) = *(short8v*)(tmp + 8);
    }
  } else {  // colsum
    int idx = task - 1024;
    int b = idx >> 2, q = idx & 3;
    int ns = tid >> 6, i4 = tid & 63;
    float4 a = {0.f, 0.f, 0.f, 0.f};
    const float4* xp = (const float4*)(x + ((size_t)b * NN + q * 128 + ns * 32) * DI) + i4;
#pragma unroll 4
    for (int n = 0; n < 32; ++n) {
      float4 v = xp[(size_t)n * 64];
      a.x += v.x; a.y += v.y; a.z += v.z; a.w += v.w;
    }
    __shared__ float4 red[4][64];
    red[ns][i4] = a;
    __syncthreads();
    if (ns == 0) {
      float4 s0 = red[0][i4], s1 = red[1][i4], s2 = red[2][i4], s3 = red[3][i4];
      float4 s;
      s.x = s0.x + s1.x + s2.x + s3.x;  s.y = s0.y + s1.y + s2.y + s3.y;
      s.z = s0.z + s1.z + s2.z + s3.z;  s.w = s0.w + s1.w + s2.w + s3.w;
      ((float4*)(xsum_p + ((size_t)q * NB + b) * DI))[i4] = s;
    }
  }
}

// ---------------------------------------------------------------------------
// k_owm: ONE block per c (64 blocks, 512 thr = 8 waves), all 16 b in the MFMA
// M dimension (no padding, no redundancy).
//  MODE 0: y = xsum/64; O = y.Kc (MFMA); squash; w = o.Kc^T (MFMA)
//  MODE 1: y = sum of 8 bf16 partials; same
//  MODE 2: y combine; O; squash -> out fp32 (no w-phase)
// LDS ybf/ob use XOR-swizzled 16B units: unit' = unit ^ (row & 7).
template <int MODE>
__global__ __launch_bounds__(512) void k_owm(const us16* __restrict__ khT,
                                             const us16* __restrict__ kh,
                                             const us16* __restrict__ yp_in,
                                             const float* __restrict__ xsum_p,
                                             us16* __restrict__ whc,
                                             float* __restrict__ outp) {
  int c = blockIdx.x;
  int tid = threadIdx.x;
  int lane = tid & 63, w = tid >> 6;
  int m16 = lane & 15, ko = lane >> 4;

  __shared__ us16 ybf[16 * 256];      // 8 KB   [b][i] swizzled
  __shared__ us16 ob[16 * 128];       // 4 KB   [b][d] swizzled
  __shared__ float o_f32[16][132];    // 8.25 KB

  // ---- y combine: thread (b = tid>>5, i8 = (tid&31)*8)
  {
    int b = tid >> 5, u = tid & 31;
    int i8 = u * 8;
    float v[8];
#pragma unroll
    for (int e = 0; e < 8; ++e) v[e] = 0.f;
    if constexpr (MODE == 0) {
#pragma unroll
      for (int q = 0; q < 4; ++q) {
        const float* sp = xsum_p + ((size_t)q * NB + b) * DI + i8;
        float4 a = *(const float4*)sp;
        float4 d = *(const float4*)(sp + 4);
        v[0] += a.x; v[1] += a.y; v[2] += a.z; v[3] += a.w;
        v[4] += d.x; v[5] += d.y; v[6] += d.z; v[7] += d.w;
      }
#pragma unroll
      for (int e = 0; e < 8; ++e) v[e] *= (1.f / 64.f);
    } else {
      const us16* base = yp_in + ((size_t)b * NC + c) * DI + i8;
#pragma unroll
      for (int p = 0; p < NP; ++p) {
        short8v t = *(const short8v*)(base + (size_t)p * (NB * NC * DI));
#pragma unroll
        for (int e = 0; e < 8; ++e) v[e] += b2f((us16)t[e]);
      }
    }
    us16 tmp[8];
#pragma unroll
    for (int e = 0; e < 8; ++e) tmp[e] = f2b(v[e]);
    *(short8v*)&ybf[b * 256 + ((u ^ (b & 7)) * 8)] = *(short8v*)tmp;
  }
  __syncthreads();

  // ---- O MFMA: wave w owns d-tile d0 = w*16; A rows = 16 b; K = 256
  {
    int d0 = w * 16;
    f32x4 acc = {0.f, 0.f, 0.f, 0.f};
#pragma unroll
    for (int kk = 0; kk < 8; ++kk) {
      int kb = kk * 4 + ko;
      short8v av = *(const short8v*)&ybf[m16 * 256 + ((kb ^ (m16 & 7)) * 8)];
      short8v bv = *(const short8v*)(khT + ((size_t)c * ND + d0 + m16) * DI + kk * 32 + ko * 8);
      acc = __builtin_amdgcn_mfma_f32_16x16x32_bf16(av, bv, acc, 0, 0, 0);
    }
    // D: col=m16 -> d_local; row=ko*4+r -> b
#pragma unroll
    for (int r = 0; r < 4; ++r) o_f32[ko * 4 + r][d0 + m16] = acc[r];
  }
  __syncthreads();

  // ---- squash: thread (b = tid>>5, j = tid&31 d-quad); reduce over 32 lanes
  {
    int b = tid >> 5, j = tid & 31;
    float4 o = *(const float4*)&o_f32[b][j * 4];
    float sq = o.x * o.x + o.y * o.y + o.z * o.z + o.w * o.w;
#pragma unroll
    for (int off = 16; off >= 1; off >>= 1) sq += __shfl_xor(sq, off, 64);
    float tot = sq + 1e-7f;
    float scale = sqrtf(tot) / (0.5f + tot);
    o.x *= scale; o.y *= scale; o.z *= scale; o.w *= scale;
    if constexpr (MODE == 2) {
      ((float4*)(outp + ((size_t)b * NC + c) * ND))[j] = o;
    } else {
      us16 tmp[4] = {f2b(o.x), f2b(o.y), f2b(o.z), f2b(o.w)};
      *(short4v*)&ob[b * 128 + (((j >> 1) ^ (b & 7)) * 8) + (j & 1) * 4] = *(short4v*)tmp;
    }
  }
  __syncthreads();

  // ---- w-phase MFMA: wave w owns i-tiles (w*2+nt)*16; K = d = 128
  if constexpr (MODE < 2) {
#pragma unroll
    for (int nt = 0; nt < 2; ++nt) {
      int i0 = (w * 2 + nt) * 16;
      f32x4 acc = {0.f, 0.f, 0.f, 0.f};
#pragma unroll
      for (int kk = 0; kk < 4; ++kk) {
        int kb = kk * 4 + ko;
        short8v av = *(const short8v*)&ob[m16 * 128 + ((kb ^ (m16 & 7)) * 8)];
        short8v bv = *(const short8v*)(kh + (size_t)(i0 + m16) * FO + c * ND + kk * 32 + ko * 8);
        acc = __builtin_amdgcn_mfma_f32_16x16x32_bf16(av, bv, acc, 0, 0, 0);
      }
      // D: col=m16 -> i_local; row=ko*4+r -> b   (all 16 rows valid!)
#pragma unroll
      for (int r = 0; r < 4; ++r)
        whc[((size_t)(ko * 4 + r) * NC + c) * DI + i0 + m16] = f2b(acc[r]);
    }
  }
}

// ---------------------------------------------------------------------------
// k_sy: block (b, p), 64-n tile, 512 thr = 8 waves.
//  logits -> softmax over c -> bf16 coef -> y partials (bf16), NP=8.
template <bool ADD_B, bool STORE_B>
__global__ __launch_bounds__(512) void k_sy(const us16* __restrict__ xh,
                                            const us16* __restrict__ xhT,
                                            const us16* __restrict__ whc,
                                            float* __restrict__ blog,
                                            us16* __restrict__ y_p) {
  int b = blockIdx.x, p = blockIdx.y;
  int tid = threadIdx.x;
  int lane = tid & 63, w = tid >> 6;
  int m16 = lane & 15, ko = lane >> 4;
  int n0 = p * 64;

  __shared__ float s_lds[64][65];   // 16.6 KB logits [n][c]
  __shared__ us16 cT[64][72];       // 9.2 KB coef [c][n]  (9x16B rows: aligned+staggered)

  // ---- logits: wave w -> Mt = w&3 (c-tile); 2 n-tiles Nt = (w>>2)*2 + t
  {
    int Mt = w & 3;
#pragma unroll
    for (int t = 0; t < 2; ++t) {
      int Nt = (w >> 2) * 2 + t;
      const us16* wrow = whc + ((size_t)b * NC + Mt * 16 + m16) * DI + ko * 8;
      const us16* xrow = xh + ((size_t)b * NN + n0 + Nt * 16 + m16) * DI + ko * 8;
      f32x4 acc = {0.f, 0.f, 0.f, 0.f};
#pragma unroll
      for (int k8 = 0; k8 < 8; ++k8) {
        short8v av = *(const short8v*)(wrow + k8 * 32);
        short8v bv = *(const short8v*)(xrow + k8 * 32);
        acc = __builtin_amdgcn_mfma_f32_16x16x32_bf16(av, bv, acc, 0, 0, 0);
      }
#pragma unroll
      for (int r = 0; r < 4; ++r)
        s_lds[Nt * 16 + m16][Mt * 16 + ko * 4 + r] = acc[r];
    }
  }
  __syncthreads();

  // ---- softmax over c (lane = c); wave w owns n = w*8 .. +7
  {
    us16 pk[8];
#pragma unroll
    for (int nn = 0; nn < 8; ++nn) {
      int n = w * 8 + nn;
      float v = s_lds[n][lane];
      size_t gi = ((size_t)b * NN + n0 + n) * NC + lane;
      if (ADD_B) v += blog[gi];
      if (STORE_B) blog[gi] = v;
      float m = v;
#pragma unroll
      for (int off = 32; off >= 1; off >>= 1) m = fmaxf(m, __shfl_xor(m, off, 64));
      float e = __expf(v - m);
      float s = e;
#pragma unroll
      for (int off = 32; off >= 1; off >>= 1) s += __shfl_xor(s, off, 64);
      pk[nn] = f2b(e / s);
    }
    *(short8v*)&cT[lane][w * 8] = *(short8v*)pk;
  }
  __syncthreads();

  // ---- y partials: wave w -> Mt2 = w&3 (c-tile); 8 i-tiles it = (w>>2)*8+q
  {
    int Mt2 = w & 3;
    short8v a0 = *(const short8v*)&cT[Mt2 * 16 + m16][ko * 8];
    short8v a1 = *(const short8v*)&cT[Mt2 * 16 + m16][32 + ko * 8];
    us16* yb = y_p + ((size_t)p * NB + b) * (NC * DI);
#pragma unroll
    for (int q = 0; q < 8; ++q) {
      int it = (w >> 2) * 8 + q;
      const us16* xr = xhT + ((size_t)b * DI + it * 16 + m16) * NN + n0;
      f32x4 acc = {0.f, 0.f, 0.f, 0.f};
      short8v bv0 = *(const short8v*)(xr + ko * 8);
      short8v bv1 = *(const short8v*)(xr + 32 + ko * 8);
      acc = __builtin_amdgcn_mfma_f32_16x16x32_bf16(a0, bv0, acc, 0, 0, 0);
      acc = __builtin_amdgcn_mfma_f32_16x16x32_bf16(a1, bv1, acc, 0, 0, 0);
#pragma unroll
      for (int r = 0; r < 4; ++r)
        yb[(size_t)(Mt2 * 16 + ko * 4 + r) * DI + it * 16 + m16] = f2b(acc[r]);
    }
  }
}

// ---------------------------------------------------------------------------
extern "C" void kernel_launch(void* const* d_in, const int* in_sizes, int n_in,
                              void* d_out, int out_size, void* d_ws, size_t ws_size,
                              hipStream_t stream) {
  (void)in_sizes; (void)n_in; (void)out_size; (void)ws_size;
  const float* x    = (const float*)d_in[0];   // [16,512,256]
  const float* kern = (const float*)d_in[1];   // [256,8192]
  float* out = (float*)d_out;                  // [16,64,128]

  char* wp = (char*)d_ws;
  us16* khT  = (us16*)wp;  wp += (size_t)NC * ND * DI * 2;       // 4 MB
  us16* kh   = (us16*)wp;  wp += (size_t)DI * FO * 2;            // 4 MB
  us16* xh   = (us16*)wp;  wp += (size_t)NB * NN * DI * 2;       // 4 MB
  us16* xhT  = (us16*)wp;  wp += (size_t)NB * DI * NN * 2;       // 4 MB
  us16* whc  = (us16*)wp;  wp += (size_t)NB * NC * DI * 2;       // 512 KB
  us16* y_p  = (us16*)wp;  wp += (size_t)NP * NB * NC * DI * 2;  // 4 MB
  float* blog   = (float*)wp;  wp += (size_t)NB * NN * NC * 4;   // 2 MB
  float* xsum_p = (float*)wp;                                    // 64 KB

  k_pre<<<1088, 256, 0, stream>>>(x, kern, khT, kh, xh, xhT, xsum_p);

  // iteration 0: uniform coef -> o0 -> w0
  k_owm<0><<<NC, 512, 0, stream>>>(khT, kh, y_p, xsum_p, whc, nullptr);
  // iteration 1
  k_sy<false, true><<<dim3(NB, NP), 512, 0, stream>>>(xh, xhT, whc, blog, y_p);
  k_owm<1><<<NC, 512, 0, stream>>>(khT, kh, y_p, xsum_p, whc, nullptr);
  // iteration 2
  k_sy<true, false><<<dim3(NB, NP), 512, 0, stream>>>(xh, xhT, whc, blog, y_p);
  k_owm<2><<<NC, 512, 0, stream>>>(khT, kh, y_p, xsum_p, whc, out);
}

// Round 11
// 55.866 us; speedup vs baseline: 1.1375x; 1.1375x over previous
//
#include <hip/hip_runtime.h>
#include <hip/hip_bf16.h>

#define NB 16   // batch
#define NN 512  // input capsules (n)
#define DI 256  // input dim (i)
#define NC 64   // output capsules (c)
#define ND 128  // capsule dim (d)
#define FO 8192 // NC*ND
#define NP 16   // n-tiles (split-k partials for y), 32 n each

typedef __attribute__((ext_vector_type(8))) short short8v;
typedef __attribute__((ext_vector_type(4))) short short4v;
typedef __attribute__((ext_vector_type(4))) float f32x4;
typedef unsigned short us16;

__device__ __forceinline__ us16 f2b(float f) {
  union { __hip_bfloat16 h; us16 u; } cv; cv.h = __float2bfloat16(f); return cv.u;
}
__device__ __forceinline__ float b2f(us16 u) {
  union { unsigned u; float f; } cv; cv.u = ((unsigned)u) << 16; return cv.f;
}

// ---------------------------------------------------------------------------
// k_pre: task-split prep.
//  [0,512):    khT[c][d][i] AND kh[i][cd] bf16 from one staged kern tile
//  [512,1024): xh[b][n][i], xhT[b][i][n] bf16 + colsum partial xsum_pp[nq][b][i]
//              (x read ONCE)
__global__ __launch_bounds__(256) void k_pre(const float* __restrict__ x,
                                             const float* __restrict__ kern,
                                             us16* __restrict__ khT,
                                             us16* __restrict__ kh,
                                             us16* __restrict__ xh,
                                             us16* __restrict__ xhT,
                                             float* __restrict__ xsum_pp) {
  int task = blockIdx.x;
  int tid = threadIdx.x;

  if (task < 512) {  // khT + kh from one staged tile
    int c = task >> 3, i0 = (task & 7) * 32;
    __shared__ float buf[32][129];
#pragma unroll
    for (int k = 0; k < 4; ++k) {
      int e4 = tid + k * 256;
      int r = e4 >> 5, dq = e4 & 31;
      float4 v = *(const float4*)(kern + (size_t)(i0 + r) * FO + c * ND + dq * 4);
      buf[r][dq * 4 + 0] = v.x; buf[r][dq * 4 + 1] = v.y;
      buf[r][dq * 4 + 2] = v.z; buf[r][dq * 4 + 3] = v.w;
    }
    __syncthreads();
#pragma unroll
    for (int k = 0; k < 16; ++k) {  // khT transpose out
      int e = tid + k * 256;
      int il = e & 31, d = e >> 5;
      khT[((size_t)c * ND + d) * DI + i0 + il] = f2b(buf[il][d]);
    }
    {  // kh same-layout cast out
      int r = tid >> 3, dg = (tid & 7) * 16;
      us16 tmp[16];
#pragma unroll
      for (int e = 0; e < 16; ++e) tmp[e] = f2b(buf[r][dg + e]);
      us16* dst = kh + (size_t)(i0 + r) * FO + c * ND + dg;
      *(short8v*)dst = *(short8v*)tmp;
      *(short8v*)(dst + 8) = *(short8v*)(tmp + 8);
    }
  } else {  // x -> xh, xhT, colsum partials (64n x 64i tile)
    int idx = task - 512;
    int b = idx >> 5, rem = idx & 31;
    int nq = rem >> 2, ib = (rem & 3) * 64;
    int nb = nq * 64;
    __shared__ float buf2[64][68];
    __shared__ float red[4][64];
#pragma unroll
    for (int k = 0; k < 4; ++k) {
      int e4 = tid + k * 256;
      int nl = e4 >> 4, q4 = e4 & 15;
      float4 v = *(const float4*)(x + ((size_t)b * NN + nb + nl) * DI + ib + q4 * 4);
      *(float4*)&buf2[nl][q4 * 4] = v;
    }
    __syncthreads();
    {  // xh row-major bf16
      int nl = tid >> 2, ig = (tid & 3) * 16;
      us16 tmp[16];
#pragma unroll
      for (int e = 0; e < 16; ++e) tmp[e] = f2b(buf2[nl][ig + e]);
      us16* dst = xh + ((size_t)b * NN + nb + nl) * DI + ib + ig;
      *(short8v*)dst = *(short8v*)tmp;
      *(short8v*)(dst + 8) = *(short8v*)(tmp + 8);
    }
    {  // xhT transposed bf16
      int il = tid & 63, ng = tid >> 6;
      us16 tmp[16];
#pragma unroll
      for (int e = 0; e < 16; ++e) tmp[e] = f2b(buf2[ng * 16 + e][il]);
      us16* dst = xhT + ((size_t)b * DI + ib + il) * NN + nb + ng * 16;
      *(short8v*)dst = *(short8v*)tmp;
      *(short8v*)(dst + 8) = *(short8v*)(tmp + 8);
    }
    {  // colsum partial over this 64-n chunk
      int il = tid & 63, rg = tid >> 6;
      float s = 0.f;
#pragma unroll
      for (int r = 0; r < 16; ++r) s += buf2[rg * 16 + r][il];
      red[rg][il] = s;
    }
    __syncthreads();
    if (tid < 64)
      xsum_pp[((size_t)nq * NB + b) * DI + ib + tid] =
          red[0][tid] + red[1][tid] + red[2][tid] + red[3][tid];
  }
}

// ---------------------------------------------------------------------------
// k_owm: block (c, b-quad), 256 blocks x 256 thr (4 waves) — r9-proven grid,
// r10-proven swizzled LDS (16B-unit ^ (row&7)).
//  MODE 0: y = sum(xsum_pp)/64 ; O = y.Kc (MFMA) ; squash ; w = o.Kc^T (MFMA)
//  MODE 1: y = sum of 16 bf16 partials ; same
//  MODE 2: y combine ; O ; squash -> out fp32 (no w-phase)
template <int MODE>
__global__ __launch_bounds__(256) void k_owm(const us16* __restrict__ khT,
                                             const us16* __restrict__ kh,
                                             const us16* __restrict__ yp_in,
                                             const float* __restrict__ xsum_pp,
                                             us16* __restrict__ whc,
                                             float* __restrict__ outp) {
  int c = blockIdx.x, b0 = blockIdx.y * 4;
  int tid = threadIdx.x;
  int lane = tid & 63, w = tid >> 6;
  int m16 = lane & 15, ko = lane >> 4;

  __shared__ us16 ybf[16 * 256];    // 8 KB  [row b 0..3 data, 4..15 zero] swizzled
  __shared__ float o_f32[4][132];   // 2.1 KB
  __shared__ us16 ob[4 * 128];      // 1 KB  swizzled

  // ---- y combine -> bf16 A rows (swizzled), zero pad rows
  {
    int bb = tid >> 6, u4 = tid & 63;   // u4: float4 index 0..63
    float4 v;
    if constexpr (MODE == 0) {
      v.x = v.y = v.z = v.w = 0.f;
#pragma unroll
      for (int q = 0; q < 8; ++q) {
        float4 t = ((const float4*)(xsum_pp + ((size_t)q * NB + b0 + bb) * DI))[u4];
        v.x += t.x; v.y += t.y; v.z += t.z; v.w += t.w;
      }
      v.x *= (1.f / 64.f); v.y *= (1.f / 64.f); v.z *= (1.f / 64.f); v.w *= (1.f / 64.f);
    } else {
      float a0 = 0.f, a1 = 0.f, a2 = 0.f, a3 = 0.f;
      const us16* base = yp_in + ((size_t)(b0 + bb) * NC + c) * DI + u4 * 4;
#pragma unroll
      for (int p = 0; p < NP; ++p) {
        short4v t = *(const short4v*)(base + (size_t)p * (NB * NC * DI));
        a0 += b2f((us16)t[0]); a1 += b2f((us16)t[1]);
        a2 += b2f((us16)t[2]); a3 += b2f((us16)t[3]);
      }
      v.x = a0; v.y = a1; v.z = a2; v.w = a3;
    }
    us16 tmp[4] = {f2b(v.x), f2b(v.y), f2b(v.z), f2b(v.w)};
    // unit = u4>>1 (8-elem 16B unit), half = u4&1 ; swizzle unit ^ (bb&7)
    *(short4v*)&ybf[bb * 256 + (((u4 >> 1) ^ bb) * 8) + (u4 & 1) * 4] = *(short4v*)tmp;
#pragma unroll
    for (int r = 0; r < 12; ++r) ybf[(4 + r) * 256 + tid] = 0;
  }
  __syncthreads();

  // ---- O MFMA: wave w owns d-tiles (w*2+nt)*16 ; A rows = 4 b + 12 zero ; K=256
  {
#pragma unroll
    for (int nt = 0; nt < 2; ++nt) {
      int d0 = (w * 2 + nt) * 16;
      f32x4 acc = {0.f, 0.f, 0.f, 0.f};
#pragma unroll
      for (int kk = 0; kk < 8; ++kk) {
        int kb = kk * 4 + ko;
        short8v av = *(const short8v*)&ybf[m16 * 256 + ((kb ^ (m16 & 7)) * 8)];
        short8v bv = *(const short8v*)(khT + ((size_t)c * ND + d0 + m16) * DI + kk * 32 + ko * 8);
        acc = __builtin_amdgcn_mfma_f32_16x16x32_bf16(av, bv, acc, 0, 0, 0);
      }
      if (ko == 0) {   // D rows 0..3 = b ; col m16 = d_local
#pragma unroll
        for (int r = 0; r < 4; ++r) o_f32[r][d0 + m16] = acc[r];
      }
    }
  }
  __syncthreads();

  // ---- squash: tid<128 (bb = tid>>5, j = tid&31 d-quad)
  if (tid < 128) {
    int bb = tid >> 5, j = tid & 31;
    float4 o = *(const float4*)&o_f32[bb][j * 4];
    float sq = o.x * o.x + o.y * o.y + o.z * o.z + o.w * o.w;
#pragma unroll
    for (int off = 16; off >= 1; off >>= 1) sq += __shfl_xor(sq, off, 64);
    float tot = sq + 1e-7f;
    float scale = sqrtf(tot) / (0.5f + tot);
    o.x *= scale; o.y *= scale; o.z *= scale; o.w *= scale;
    if constexpr (MODE == 2) {
      ((float4*)(outp + ((size_t)(b0 + bb) * NC + c) * ND))[j] = o;
    } else {
      us16 tmp[4] = {f2b(o.x), f2b(o.y), f2b(o.z), f2b(o.w)};
      *(short4v*)&ob[bb * 128 + (((j >> 1) ^ bb) * 8) + (j & 1) * 4] = *(short4v*)tmp;
    }
  }
  __syncthreads();

  // ---- w-phase MFMA: wave w owns i-tiles (w*4+nt)*16 ; K = d = 128
  if constexpr (MODE < 2) {
#pragma unroll
    for (int nt = 0; nt < 4; ++nt) {
      int i0 = (w * 4 + nt) * 16;
      f32x4 acc = {0.f, 0.f, 0.f, 0.f};
#pragma unroll
      for (int kk = 0; kk < 4; ++kk) {
        int kb = kk * 4 + ko;
        short8v av = *(const short8v*)&ob[(m16 & 3) * 128 + ((kb ^ (m16 & 3)) * 8)];
        short8v bv = *(const short8v*)(kh + (size_t)(i0 + m16) * FO + c * ND + kk * 32 + ko * 8);
        acc = __builtin_amdgcn_mfma_f32_16x16x32_bf16(av, bv, acc, 0, 0, 0);
      }
      if (ko == 0) {   // D rows 0..3 = b ; col m16 = i_local
#pragma unroll
        for (int r = 0; r < 4; ++r)
          whc[((size_t)(b0 + r) * NC + c) * DI + i0 + m16] = f2b(acc[r]);
      }
    }
  }
}

// ---------------------------------------------------------------------------
// k_sy: block (b, p), 32-n tile, 512 thr = 8 waves — r9-proven (NP=16).
//  logits -> softmax over c -> bf16 coef -> y partials (bf16).
template <bool ADD_B, bool STORE_B>
__global__ __launch_bounds__(512) void k_sy(const us16* __restrict__ xh,
                                            const us16* __restrict__ xhT,
                                            const us16* __restrict__ whc,
                                            float* __restrict__ blog,
                                            us16* __restrict__ y_p) {
  int b = blockIdx.x, p = blockIdx.y;
  int tid = threadIdx.x;
  int lane = tid & 63, w = tid >> 6;
  int m16 = lane & 15, ko = lane >> 4;
  int n0 = p * 32;

  __shared__ float s_lds[32][65];
  __shared__ us16 cT[64][40];

  {  // logits sT[c][n]: wave w -> Mt = w&3 (c-tile), Nt = w>>2 (n-tile)
    int Mt = w & 3, Nt = w >> 2;
    const us16* wrow = whc + ((size_t)b * NC + Mt * 16 + m16) * DI + ko * 8;
    const us16* xrow = xh + ((size_t)b * NN + n0 + Nt * 16 + m16) * DI + ko * 8;
    f32x4 acc = {0.f, 0.f, 0.f, 0.f};
#pragma unroll
    for (int k8 = 0; k8 < 8; ++k8) {
      short8v av = *(const short8v*)(wrow + k8 * 32);
      short8v bv = *(const short8v*)(xrow + k8 * 32);
      acc = __builtin_amdgcn_mfma_f32_16x16x32_bf16(av, bv, acc, 0, 0, 0);
    }
#pragma unroll
    for (int r = 0; r < 4; ++r)
      s_lds[Nt * 16 + m16][Mt * 16 + ko * 4 + r] = acc[r];
  }
  __syncthreads();

  {  // softmax over c (lane = c); wave w owns n = w*4..+3
    us16 pk[4];
#pragma unroll
    for (int nn = 0; nn < 4; ++nn) {
      int n = w * 4 + nn;
      float v = s_lds[n][lane];
      size_t gi = ((size_t)b * NN + n0 + n) * NC + lane;
      if (ADD_B) v += blog[gi];
      if (STORE_B) blog[gi] = v;
      float m = v;
#pragma unroll
      for (int off = 32; off >= 1; off >>= 1) m = fmaxf(m, __shfl_xor(m, off, 64));
      float e = __expf(v - m);
      float s = e;
#pragma unroll
      for (int off = 32; off >= 1; off >>= 1) s += __shfl_xor(s, off, 64);
      pk[nn] = f2b(e / s);
    }
    *(short4v*)&cT[lane][w * 4] = *(short4v*)pk;
  }
  __syncthreads();

  {  // y partials (bf16): wave w -> Mp = w>>2 (2 c-tiles), Ng = w&3 (4 i-tiles)
    int Mp = w >> 2, Ng = w & 3;
    short8v a0 = *(const short8v*)&cT[(Mp * 2 + 0) * 16 + m16][ko * 8];
    short8v a1 = *(const short8v*)&cT[(Mp * 2 + 1) * 16 + m16][ko * 8];
    f32x4 acc[2][4];
#pragma unroll
    for (int t = 0; t < 2; ++t)
#pragma unroll
      for (int q = 0; q < 4; ++q) { acc[t][q][0]=acc[t][q][1]=acc[t][q][2]=acc[t][q][3]=0.f; }
#pragma unroll
    for (int q = 0; q < 4; ++q) {
      int icol = (Ng * 4 + q) * 16 + m16;
      short8v bv = *(const short8v*)(xhT + ((size_t)b * DI + icol) * NN + n0 + ko * 8);
      acc[0][q] = __builtin_amdgcn_mfma_f32_16x16x32_bf16(a0, bv, acc[0][q], 0, 0, 0);
      acc[1][q] = __builtin_amdgcn_mfma_f32_16x16x32_bf16(a1, bv, acc[1][q], 0, 0, 0);
    }
    us16* yb = y_p + ((size_t)p * NB + b) * (NC * DI);
#pragma unroll
    for (int t = 0; t < 2; ++t)
#pragma unroll
      for (int q = 0; q < 4; ++q)
#pragma unroll
        for (int r = 0; r < 4; ++r)
          yb[(size_t)((Mp * 2 + t) * 16 + ko * 4 + r) * DI + (Ng * 4 + q) * 16 + m16] =
              f2b(acc[t][q][r]);
  }
}

// ---------------------------------------------------------------------------
extern "C" void kernel_launch(void* const* d_in, const int* in_sizes, int n_in,
                              void* d_out, int out_size, void* d_ws, size_t ws_size,
                              hipStream_t stream) {
  (void)in_sizes; (void)n_in; (void)out_size; (void)ws_size;
  const float* x    = (const float*)d_in[0];   // [16,512,256]
  const float* kern = (const float*)d_in[1];   // [256,8192]
  float* out = (float*)d_out;                  // [16,64,128]

  char* wp = (char*)d_ws;
  us16* khT  = (us16*)wp;  wp += (size_t)NC * ND * DI * 2;       // 4 MB
  us16* kh   = (us16*)wp;  wp += (size_t)DI * FO * 2;            // 4 MB
  us16* xh   = (us16*)wp;  wp += (size_t)NB * NN * DI * 2;       // 4 MB
  us16* xhT  = (us16*)wp;  wp += (size_t)NB * DI * NN * 2;       // 4 MB
  us16* whc  = (us16*)wp;  wp += (size_t)NB * NC * DI * 2;       // 512 KB
  us16* y_p  = (us16*)wp;  wp += (size_t)NP * NB * NC * DI * 2;  // 8 MB
  float* blog    = (float*)wp;  wp += (size_t)NB * NN * NC * 4;  // 2 MB
  float* xsum_pp = (float*)wp;                                   // 512 KB

  k_pre<<<1024, 256, 0, stream>>>(x, kern, khT, kh, xh, xhT, xsum_pp);

  // iteration 0: uniform coef -> o0 -> w0
  k_owm<0><<<dim3(NC, 4), 256, 0, stream>>>(khT, kh, y_p, xsum_pp, whc, nullptr);
  // iteration 1
  k_sy<false, true><<<dim3(NB, NP), 512, 0, stream>>>(xh, xhT, whc, blog, y_p);
  k_owm<1><<<dim3(NC, 4), 256, 0, stream>>>(khT, kh, y_p, xsum_pp, whc, nullptr);
  // iteration 2
  k_sy<true, false><<<dim3(NB, NP), 512, 0, stream>>>(xh, xhT, whc, blog, y_p);
  k_owm<2><<<dim3(NC, 4), 256, 0, stream>>>(khT, kh, y_p, xsum_pp, whc, out);
}

// Round 12
// 55.729 us; speedup vs baseline: 1.1403x; 1.0025x over previous
//
#include <hip/hip_runtime.h>
#include <hip/hip_bf16.h>

#define NB 16   // batch
#define NN 512  // input capsules (n)
#define DI 256  // input dim (i)
#define NC 64   // output capsules (c)
#define ND 128  // capsule dim (d)
#define FO 8192 // NC*ND
#define NP 16   // n-tiles (split-k partials for y), 32 n each

typedef __attribute__((ext_vector_type(8))) short short8v;
typedef __attribute__((ext_vector_type(4))) short short4v;
typedef __attribute__((ext_vector_type(4))) float f32x4;
typedef unsigned short us16;

__device__ __forceinline__ us16 f2b(float f) {
  union { __hip_bfloat16 h; us16 u; } cv; cv.h = __float2bfloat16(f); return cv.u;
}
__device__ __forceinline__ float b2f(us16 u) {
  union { unsigned u; float f; } cv; cv.u = ((unsigned)u) << 16; return cv.f;
}

// ---------------------------------------------------------------------------
// k_pre: task-split prep.
//  [0,512):    khT[c][d][i] AND kh[i][cd] bf16 from one staged kern tile
//  [512,1024): xh[b][n][i], xhT[b][i][n] bf16 + colsum partial xsum_pp[nq][b][i]
//              (x read ONCE)
__global__ __launch_bounds__(256) void k_pre(const float* __restrict__ x,
                                             const float* __restrict__ kern,
                                             us16* __restrict__ khT,
                                             us16* __restrict__ kh,
                                             us16* __restrict__ xh,
                                             us16* __restrict__ xhT,
                                             float* __restrict__ xsum_pp) {
  int task = blockIdx.x;
  int tid = threadIdx.x;

  if (task < 512) {  // khT + kh from one staged tile
    int c = task >> 3, i0 = (task & 7) * 32;
    __shared__ float buf[32][129];
#pragma unroll
    for (int k = 0; k < 4; ++k) {
      int e4 = tid + k * 256;
      int r = e4 >> 5, dq = e4 & 31;
      float4 v = *(const float4*)(kern + (size_t)(i0 + r) * FO + c * ND + dq * 4);
      buf[r][dq * 4 + 0] = v.x; buf[r][dq * 4 + 1] = v.y;
      buf[r][dq * 4 + 2] = v.z; buf[r][dq * 4 + 3] = v.w;
    }
    __syncthreads();
#pragma unroll
    for (int k = 0; k < 16; ++k) {  // khT transpose out
      int e = tid + k * 256;
      int il = e & 31, d = e >> 5;
      khT[((size_t)c * ND + d) * DI + i0 + il] = f2b(buf[il][d]);
    }
    {  // kh same-layout cast out
      int r = tid >> 3, dg = (tid & 7) * 16;
      us16 tmp[16];
#pragma unroll
      for (int e = 0; e < 16; ++e) tmp[e] = f2b(buf[r][dg + e]);
      us16* dst = kh + (size_t)(i0 + r) * FO + c * ND + dg;
      *(short8v*)dst = *(short8v*)tmp;
      *(short8v*)(dst + 8) = *(short8v*)(tmp + 8);
    }
  } else {  // x -> xh, xhT, colsum partials (64n x 64i tile)
    int idx = task - 512;
    int b = idx >> 5, rem = idx & 31;
    int nq = rem >> 2, ib = (rem & 3) * 64;
    int nb = nq * 64;
    __shared__ float buf2[64][68];
    __shared__ float red[4][64];
#pragma unroll
    for (int k = 0; k < 4; ++k) {
      int e4 = tid + k * 256;
      int nl = e4 >> 4, q4 = e4 & 15;
      float4 v = *(const float4*)(x + ((size_t)b * NN + nb + nl) * DI + ib + q4 * 4);
      *(float4*)&buf2[nl][q4 * 4] = v;
    }
    __syncthreads();
    {  // xh row-major bf16
      int nl = tid >> 2, ig = (tid & 3) * 16;
      us16 tmp[16];
#pragma unroll
      for (int e = 0; e < 16; ++e) tmp[e] = f2b(buf2[nl][ig + e]);
      us16* dst = xh + ((size_t)b * NN + nb + nl) * DI + ib + ig;
      *(short8v*)dst = *(short8v*)tmp;
      *(short8v*)(dst + 8) = *(short8v*)(tmp + 8);
    }
    {  // xhT transposed bf16
      int il = tid & 63, ng = tid >> 6;
      us16 tmp[16];
#pragma unroll
      for (int e = 0; e < 16; ++e) tmp[e] = f2b(buf2[ng * 16 + e][il]);
      us16* dst = xhT + ((size_t)b * DI + ib + il) * NN + nb + ng * 16;
      *(short8v*)dst = *(short8v*)tmp;
      *(short8v*)(dst + 8) = *(short8v*)(tmp + 8);
    }
    {  // colsum partial over this 64-n chunk
      int il = tid & 63, rg = tid >> 6;
      float s = 0.f;
#pragma unroll
      for (int r = 0; r < 16; ++r) s += buf2[rg * 16 + r][il];
      red[rg][il] = s;
    }
    __syncthreads();
    if (tid < 64)
      xsum_pp[((size_t)nq * NB + b) * DI + ib + tid] =
          red[0][tid] + red[1][tid] + red[2][tid] + red[3][tid];
  }
}

// ---------------------------------------------------------------------------
// k_owm: block (c, b-quad), 256 blocks x 256 thr (4 waves).
//  MODE 0: y = sum(xsum_pp)/64 ; O = y.Kc (MFMA) ; squash ; whc  = w0
//  MODE 1: y = sum of 16 bf16 partials ; same ;   whc += w1  (in-place fp32 acc
//          -> logits2 = x.(w0+w1) directly, no blog needed since b0 == 0)
//  MODE 2: y combine ; O ; squash -> out fp32 (no w-phase)
template <int MODE>
__global__ __launch_bounds__(256) void k_owm(const us16* __restrict__ khT,
                                             const us16* __restrict__ kh,
                                             const us16* __restrict__ yp_in,
                                             const float* __restrict__ xsum_pp,
                                             us16* __restrict__ whc,
                                             float* __restrict__ outp) {
  int c = blockIdx.x, b0 = blockIdx.y * 4;
  int tid = threadIdx.x;
  int lane = tid & 63, w = tid >> 6;
  int m16 = lane & 15, ko = lane >> 4;

  __shared__ us16 ybf[16 * 256];    // 8 KB  [row b 0..3 data, 4..15 zero] swizzled
  __shared__ float o_f32[4][132];   // 2.1 KB
  __shared__ us16 ob[4 * 128];      // 1 KB  swizzled

  // ---- y combine -> bf16 A rows (swizzled), zero pad rows
  {
    int bb = tid >> 6, u4 = tid & 63;   // u4: float4 index 0..63
    float4 v;
    if constexpr (MODE == 0) {
      v.x = v.y = v.z = v.w = 0.f;
#pragma unroll
      for (int q = 0; q < 8; ++q) {
        float4 t = ((const float4*)(xsum_pp + ((size_t)q * NB + b0 + bb) * DI))[u4];
        v.x += t.x; v.y += t.y; v.z += t.z; v.w += t.w;
      }
      v.x *= (1.f / 64.f); v.y *= (1.f / 64.f); v.z *= (1.f / 64.f); v.w *= (1.f / 64.f);
    } else {
      float a0 = 0.f, a1 = 0.f, a2 = 0.f, a3 = 0.f;
      const us16* base = yp_in + ((size_t)(b0 + bb) * NC + c) * DI + u4 * 4;
#pragma unroll
      for (int p = 0; p < NP; ++p) {
        short4v t = *(const short4v*)(base + (size_t)p * (NB * NC * DI));
        a0 += b2f((us16)t[0]); a1 += b2f((us16)t[1]);
        a2 += b2f((us16)t[2]); a3 += b2f((us16)t[3]);
      }
      v.x = a0; v.y = a1; v.z = a2; v.w = a3;
    }
    us16 tmp[4] = {f2b(v.x), f2b(v.y), f2b(v.z), f2b(v.w)};
    // unit = u4>>1 (8-elem 16B unit), half = u4&1 ; swizzle unit ^ (bb&7)
    *(short4v*)&ybf[bb * 256 + (((u4 >> 1) ^ bb) * 8) + (u4 & 1) * 4] = *(short4v*)tmp;
#pragma unroll
    for (int r = 0; r < 12; ++r) ybf[(4 + r) * 256 + tid] = 0;
  }
  __syncthreads();

  // ---- O MFMA: wave w owns d-tiles (w*2+nt)*16 ; A rows = 4 b + 12 zero ; K=256
  {
#pragma unroll
    for (int nt = 0; nt < 2; ++nt) {
      int d0 = (w * 2 + nt) * 16;
      f32x4 acc = {0.f, 0.f, 0.f, 0.f};
#pragma unroll
      for (int kk = 0; kk < 8; ++kk) {
        int kb = kk * 4 + ko;
        short8v av = *(const short8v*)&ybf[m16 * 256 + ((kb ^ (m16 & 7)) * 8)];
        short8v bv = *(const short8v*)(khT + ((size_t)c * ND + d0 + m16) * DI + kk * 32 + ko * 8);
        acc = __builtin_amdgcn_mfma_f32_16x16x32_bf16(av, bv, acc, 0, 0, 0);
      }
      if (ko == 0) {   // D rows 0..3 = b ; col m16 = d_local
#pragma unroll
        for (int r = 0; r < 4; ++r) o_f32[r][d0 + m16] = acc[r];
      }
    }
  }
  __syncthreads();

  // ---- squash: tid<128 (bb = tid>>5, j = tid&31 d-quad)
  if (tid < 128) {
    int bb = tid >> 5, j = tid & 31;
    float4 o = *(const float4*)&o_f32[bb][j * 4];
    float sq = o.x * o.x + o.y * o.y + o.z * o.z + o.w * o.w;
#pragma unroll
    for (int off = 16; off >= 1; off >>= 1) sq += __shfl_xor(sq, off, 64);
    float tot = sq + 1e-7f;
    float scale = sqrtf(tot) / (0.5f + tot);
    o.x *= scale; o.y *= scale; o.z *= scale; o.w *= scale;
    if constexpr (MODE == 2) {
      ((float4*)(outp + ((size_t)(b0 + bb) * NC + c) * ND))[j] = o;
    } else {
      us16 tmp[4] = {f2b(o.x), f2b(o.y), f2b(o.z), f2b(o.w)};
      *(short4v*)&ob[bb * 128 + (((j >> 1) ^ bb) * 8) + (j & 1) * 4] = *(short4v*)tmp;
    }
  }
  __syncthreads();

  // ---- w-phase MFMA: wave w owns i-tiles (w*4+nt)*16 ; K = d = 128
  if constexpr (MODE < 2) {
#pragma unroll
    for (int nt = 0; nt < 4; ++nt) {
      int i0 = (w * 4 + nt) * 16;
      f32x4 acc = {0.f, 0.f, 0.f, 0.f};
#pragma unroll
      for (int kk = 0; kk < 4; ++kk) {
        int kb = kk * 4 + ko;
        short8v av = *(const short8v*)&ob[(m16 & 3) * 128 + ((kb ^ (m16 & 3)) * 8)];
        short8v bv = *(const short8v*)(kh + (size_t)(i0 + m16) * FO + c * ND + kk * 32 + ko * 8);
        acc = __builtin_amdgcn_mfma_f32_16x16x32_bf16(av, bv, acc, 0, 0, 0);
      }
      if (ko == 0) {   // D rows 0..3 = b ; col m16 = i_local
#pragma unroll
        for (int r = 0; r < 4; ++r) {
          size_t idx = ((size_t)(b0 + r) * NC + c) * DI + i0 + m16;
          float wv = acc[r];
          if constexpr (MODE == 1) wv += b2f(whc[idx]);  // accumulate w0 + w1
          whc[idx] = f2b(wv);
        }
      }
    }
  }
}

// ---------------------------------------------------------------------------
// k_sy: block (b, p), 32-n tile, 512 thr = 8 waves.
//  logits = x.whc -> softmax over c -> bf16 coef -> y partials (bf16).
//  No blog: iteration-2 logits come from accumulated whc (w0+w1).
__global__ __launch_bounds__(512) void k_sy(const us16* __restrict__ xh,
                                            const us16* __restrict__ xhT,
                                            const us16* __restrict__ whc,
                                            us16* __restrict__ y_p) {
  int b = blockIdx.x, p = blockIdx.y;
  int tid = threadIdx.x;
  int lane = tid & 63, w = tid >> 6;
  int m16 = lane & 15, ko = lane >> 4;
  int n0 = p * 32;

  __shared__ float s_lds[32][65];
  __shared__ us16 cT[64][40];

  {  // logits sT[c][n]: wave w -> Mt = w&3 (c-tile), Nt = w>>2 (n-tile)
    int Mt = w & 3, Nt = w >> 2;
    const us16* wrow = whc + ((size_t)b * NC + Mt * 16 + m16) * DI + ko * 8;
    const us16* xrow = xh + ((size_t)b * NN + n0 + Nt * 16 + m16) * DI + ko * 8;
    f32x4 acc = {0.f, 0.f, 0.f, 0.f};
#pragma unroll
    for (int k8 = 0; k8 < 8; ++k8) {
      short8v av = *(const short8v*)(wrow + k8 * 32);
      short8v bv = *(const short8v*)(xrow + k8 * 32);
      acc = __builtin_amdgcn_mfma_f32_16x16x32_bf16(av, bv, acc, 0, 0, 0);
    }
#pragma unroll
    for (int r = 0; r < 4; ++r)
      s_lds[Nt * 16 + m16][Mt * 16 + ko * 4 + r] = acc[r];
  }
  __syncthreads();

  {  // softmax over c (lane = c); wave w owns n = w*4..+3
    us16 pk[4];
#pragma unroll
    for (int nn = 0; nn < 4; ++nn) {
      int n = w * 4 + nn;
      float v = s_lds[n][lane];
      float m = v;
#pragma unroll
      for (int off = 32; off >= 1; off >>= 1) m = fmaxf(m, __shfl_xor(m, off, 64));
      float e = __expf(v - m);
      float s = e;
#pragma unroll
      for (int off = 32; off >= 1; off >>= 1) s += __shfl_xor(s, off, 64);
      pk[nn] = f2b(e / s);
    }
    *(short4v*)&cT[lane][w * 4] = *(short4v*)pk;
  }
  __syncthreads();

  {  // y partials (bf16): wave w -> Mp = w>>2 (2 c-tiles), Ng = w&3 (4 i-tiles)
    int Mp = w >> 2, Ng = w & 3;
    short8v a0 = *(const short8v*)&cT[(Mp * 2 + 0) * 16 + m16][ko * 8];
    short8v a1 = *(const short8v*)&cT[(Mp * 2 + 1) * 16 + m16][ko * 8];
    f32x4 acc[2][4];
#pragma unroll
    for (int t = 0; t < 2; ++t)
#pragma unroll
      for (int q = 0; q < 4; ++q) { acc[t][q][0]=acc[t][q][1]=acc[t][q][2]=acc[t][q][3]=0.f; }
#pragma unroll
    for (int q = 0; q < 4; ++q) {
      int icol = (Ng * 4 + q) * 16 + m16;
      short8v bv = *(const short8v*)(xhT + ((size_t)b * DI + icol) * NN + n0 + ko * 8);
      acc[0][q] = __builtin_amdgcn_mfma_f32_16x16x32_bf16(a0, bv, acc[0][q], 0, 0, 0);
      acc[1][q] = __builtin_amdgcn_mfma_f32_16x16x32_bf16(a1, bv, acc[1][q], 0, 0, 0);
    }
    us16* yb = y_p + ((size_t)p * NB + b) * (NC * DI);
#pragma unroll
    for (int t = 0; t < 2; ++t)
#pragma unroll
      for (int q = 0; q < 4; ++q)
#pragma unroll
        for (int r = 0; r < 4; ++r)
          yb[(size_t)((Mp * 2 + t) * 16 + ko * 4 + r) * DI + (Ng * 4 + q) * 16 + m16] =
              f2b(acc[t][q][r]);
  }
}

// ---------------------------------------------------------------------------
extern "C" void kernel_launch(void* const* d_in, const int* in_sizes, int n_in,
                              void* d_out, int out_size, void* d_ws, size_t ws_size,
                              hipStream_t stream) {
  (void)in_sizes; (void)n_in; (void)out_size; (void)ws_size;
  const float* x    = (const float*)d_in[0];   // [16,512,256]
  const float* kern = (const float*)d_in[1];   // [256,8192]
  float* out = (float*)d_out;                  // [16,64,128]

  char* wp = (char*)d_ws;
  us16* khT  = (us16*)wp;  wp += (size_t)NC * ND * DI * 2;       // 4 MB
  us16* kh   = (us16*)wp;  wp += (size_t)DI * FO * 2;            // 4 MB
  us16* xh   = (us16*)wp;  wp += (size_t)NB * NN * DI * 2;       // 4 MB
  us16* xhT  = (us16*)wp;  wp += (size_t)NB * DI * NN * 2;       // 4 MB
  us16* whc  = (us16*)wp;  wp += (size_t)NB * NC * DI * 2;       // 512 KB
  us16* y_p  = (us16*)wp;  wp += (size_t)NP * NB * NC * DI * 2;  // 8 MB
  float* xsum_pp = (float*)wp;                                   // 512 KB

  k_pre<<<1024, 256, 0, stream>>>(x, kern, khT, kh, xh, xhT, xsum_pp);

  // iteration 0: uniform coef -> o0 -> whc = w0
  k_owm<0><<<dim3(NC, 4), 256, 0, stream>>>(khT, kh, y_p, xsum_pp, whc, nullptr);
  // iteration 1: coef1 = softmax(x.w0) -> y1 partials
  k_sy<<<dim3(NB, NP), 512, 0, stream>>>(xh, xhT, whc, y_p);
  // o1 -> whc = w0 + w1
  k_owm<1><<<dim3(NC, 4), 256, 0, stream>>>(khT, kh, y_p, xsum_pp, whc, nullptr);
  // iteration 2: coef2 = softmax(x.(w0+w1)) -> y2 partials
  k_sy<<<dim3(NB, NP), 512, 0, stream>>>(xh, xhT, whc, y_p);
  // final: o2 -> out
  k_owm<2><<<dim3(NC, 4), 256, 0, stream>>>(khT, kh, y_p, xsum_pp, whc, out);
}